// Round 1
// baseline (2005.727 us; speedup 1.0000x reference)
//
#include <hip/hip_runtime.h>

typedef __attribute__((ext_vector_type(4))) float  f32x4;
typedef __attribute__((ext_vector_type(8))) short  short8;
typedef __attribute__((ext_vector_type(4))) int    i32x4;
typedef __attribute__((ext_vector_type(2))) int    i32x2;

#define LOG2E 1.4426950408889634f

__device__ __forceinline__ float fexp2(float x){ float r; asm("v_exp_f32 %0, %1" : "=v"(r) : "v"(x)); return r; }
__device__ __forceinline__ float frcp (float x){ float r; asm("v_rcp_f32 %0, %1" : "=v"(r) : "v"(x)); return r; }
__device__ __forceinline__ float fsigmoid(float x){ return frcp(1.f + fexp2(-LOG2E*x)); }
__device__ __forceinline__ float ftanhf (float x){ return 1.f - 2.f*frcp(1.f + fexp2(2.f*LOG2E*x)); }

__device__ __forceinline__ unsigned short f2bf(float f){
  unsigned u = __builtin_bit_cast(unsigned, f);
  u = u + 0x7FFFu + ((u >> 16) & 1u);
  return (unsigned short)(u >> 16);
}
__device__ __forceinline__ float bf2f(unsigned short h){
  unsigned u = ((unsigned)h) << 16;
  return __builtin_bit_cast(float, u);
}

// ---------------- fused prep ----------------
// blocks [0,6144): x cast; [6144,6912): Wih_f; [6912,7680): Wih_b; [7680,8192): W3;
// [8192,8320): pack_w1; [8320,8328): pack_bias.
__global__ __launch_bounds__(256) void prep_fused(
    const float* __restrict__ x,     unsigned short* __restrict__ x_bf,
    const float* __restrict__ Wih_f, const float* __restrict__ Wih_b,
    unsigned short* __restrict__ wihcat,
    const float* __restrict__ W3,    unsigned short* __restrict__ w3bf,
    const float* __restrict__ W1,    unsigned short* __restrict__ w1p,
    const float* __restrict__ bif, const float* __restrict__ bhf,
    const float* __restrict__ bib, const float* __restrict__ bhb,
    float* __restrict__ bc)
{
  const int bid = blockIdx.x, tid = threadIdx.x;
  if (bid < 8192){
    const float* s; unsigned short* d; int i;
    if (bid < 6144)      { s = x;     d = x_bf;            i = bid * 256 + tid; }
    else if (bid < 6912) { s = Wih_f; d = wihcat;          i = (bid - 6144) * 256 + tid; }
    else if (bid < 7680) { s = Wih_b; d = wihcat + 786432; i = (bid - 6912) * 256 + tid; }
    else                 { s = W3;    d = w3bf;            i = (bid - 7680) * 256 + tid; }
    float4 f = ((const float4*)s)[i];
    uint2 o;
    o.x = (unsigned)f2bf(f.x) | ((unsigned)f2bf(f.y) << 16);
    o.y = (unsigned)f2bf(f.z) | ((unsigned)f2bf(f.w) << 16);
    ((uint2*)d)[i] = o;
  } else if (bid < 8320){
    int i = (bid - 8192) * 256 + tid;           // 0..32767
    int r = i >> 9, c = i & 511;
    float v = 0.f;
    if (r < 10) v = W1[r * 1024 + c];
    else if (r >= 16 && r < 26) v = W1[(r - 16) * 1024 + 512 + c];
    w1p[i] = f2bf(v);
  } else {
    int i = (bid - 8320) * 256 + tid;           // 0..2047
    if (i < 1024) bc[i] = bif[i] + bhf[i];
    else          bc[i] = bib[i - 1024] + bhb[i - 1024];
  }
}

// ---------------- generic bf16 GEMM: C[M,N] = A[M,K] @ B[N,K]^T (+bias) ----------------
// omode: 0 = f32 out, 1 = bf16 out, 2 = bf16 scan-layout scatter
//        (xgp[(d*2+half)][t][b*512 + ul*4 + gate])
__global__ __launch_bounds__(256) void gemm_abt(
    const unsigned short* __restrict__ A, long lda, long sAz,
    const unsigned short* __restrict__ B, long ldb, long sBz,
    const float* __restrict__ bias,
    void* __restrict__ Cv, long ldc, long sCz,
    int M, int N, int K, int omode)
{
  __shared__ __align__(16) unsigned short As[128 * 40];
  __shared__ __align__(16) unsigned short Bs[128 * 40];
  const int tid = threadIdx.x;
  const int m0 = blockIdx.y * 128;
  const int n0 = blockIdx.x * 128;
  const long z = blockIdx.z;
  A += z * sAz; B += z * sBz;
  const int w = tid >> 6, l = tid & 63;
  const int wm = (w >> 1) * 64, wn = (w & 1) * 64;
  const int lm = l & 15, lq = l >> 4;
  f32x4 acc[4][4] = {};
  const int sr = tid >> 1;
  const int sk = (tid & 1) * 16;
  const unsigned short* Aptr = A + (long)(m0 + sr) * lda + sk;
  const unsigned short* Bptr = B + (long)(n0 + sr) * ldb + sk;
  const bool bvalid = (n0 + sr) < N;
  const int KB = K >> 5;
  for (int kb = 0; kb < KB; ++kb){
    i32x4 av0 = *(const i32x4*)(Aptr);
    i32x4 av1 = *(const i32x4*)(Aptr + 8);
    i32x4 bv0 = {0,0,0,0}, bv1 = {0,0,0,0};
    if (bvalid){ bv0 = *(const i32x4*)(Bptr); bv1 = *(const i32x4*)(Bptr + 8); }
    Aptr += 32; Bptr += 32;
    __syncthreads();
    *(i32x4*)&As[sr * 40 + sk] = av0;  *(i32x4*)&As[sr * 40 + sk + 8] = av1;
    *(i32x4*)&Bs[sr * 40 + sk] = bv0;  *(i32x4*)&Bs[sr * 40 + sk + 8] = bv1;
    __syncthreads();
    const int koff = lq * 8;
    short8 af[4], bf[4];
    #pragma unroll
    for (int mt = 0; mt < 4; ++mt) af[mt] = *(short8*)&As[(wm + mt * 16 + lm) * 40 + koff];
    #pragma unroll
    for (int nt = 0; nt < 4; ++nt) bf[nt] = *(short8*)&Bs[(wn + nt * 16 + lm) * 40 + koff];
    #pragma unroll
    for (int mt = 0; mt < 4; ++mt)
      #pragma unroll
      for (int nt = 0; nt < 4; ++nt)
        acc[mt][nt] = __builtin_amdgcn_mfma_f32_16x16x32_bf16(af[mt], bf[nt], acc[mt][nt], 0, 0, 0);
  }
  #pragma unroll
  for (int mt = 0; mt < 4; ++mt){
    const int mbase = m0 + wm + mt * 16 + lq * 4;
    #pragma unroll
    for (int nt = 0; nt < 4; ++nt){
      const int n = n0 + wn + nt * 16 + lm;
      if (n < N){
        const float bv = bias ? bias[n] : 0.f;
        #pragma unroll
        for (int r = 0; r < 4; ++r){
          const float v = acc[mt][nt][r] + bv;
          const int m = mbase + r;
          if (omode == 2){
            const int b = m >> 10, tt = m & 1023;
            const int dd = n >> 10, gate = (n >> 8) & 3, unit = n & 255;
            const int hf = unit >> 7, ul = unit & 127;
            const long idx = ((long)(dd * 2 + hf) * 1024 + tt) * 4096 + b * 512 + ul * 4 + gate;
            ((unsigned short*)Cv)[idx] = f2bf(v);
          } else {
            const long idx = z * sCz + (long)m * ldc + n;
            if (omode == 1) ((unsigned short*)Cv)[idx] = f2bf(v);
            else            ((float*)Cv)[idx] = v;
          }
        }
      }
    }
  }
}

// ---------------- LSTM scan v10: 4 blocks (2 per dir), partner-only exchange ----------------
// Block = (dir d, unit-half). 512 threads = 8 waves. Whh rows for this block's
// 128 units x 4 gates (gate-interleaved cols: n = ul*4+gate) live ENTIRELY in
// registers: bfr[4][8] = 128 VGPR/thread. Own half of h(t) is kept in LDS; only
// the partner's 2 KB half crosses global per step (tagged qwords, sc0/sc1).
// K-reduction is split so own-half MFMAs run while the partner poll is in flight.
// hexd layout: [d][t][half*512 + b*64 + P] qwords, payload hi = h[2P]|h[2P+1]<<16
// (units local to the half) -> same footprint as before; repack adapted.
__global__ __launch_bounds__(512, 2) void lstm_scan(
    const unsigned short* __restrict__ xgp,  // [(d*2+half)][t][b*512 + ul*4 + gate] bf16
    const float* __restrict__ Whh_f, const float* __restrict__ Whh_b,
    unsigned long long* __restrict__ hexd)   // [2][1024][1024] tagged qwords
{
  const int d    = blockIdx.x >> 1;
  const int half = blockIdx.x & 1;
  const int tid  = threadIdx.x;
  const int w    = tid >> 6;                 // wave 0..7
  const int l    = tid & 63;
  const int lm   = l & 15;
  const int lq   = l >> 4;
  const float* Whh = d ? Whh_b : Whh_f;

  __shared__ __align__(16) unsigned short Abuf[8 * 264];   // h(t-1): [b][u(256) pad264]
  __shared__ __align__(16) float gbuf[8 * 516];            // gates:  [b][col(512) pad516]

  for (int i = tid; i < 1056; i += 512) ((unsigned*)Abuf)[i] = 0;

  // resident B fragments: wave w covers cols [w*64, w*64+64). col = ul*4+gate.
  // k-slice order is rotated so kk=0..3 touch the OWN unit-half of h first.
  short8 bfr[4][8];
  #pragma unroll
  for (int nt = 0; nt < 4; ++nt){
    const int ncol = w * 64 + nt * 16 + lm;
    const long row = (long)((ncol & 3) * 256 + half * 128 + (ncol >> 2)) * 256;
    #pragma unroll
    for (int kk = 0; kk < 8; ++kk){
      const int ks = ((half << 2) + kk) & 7;
      const float* wr = Whh + row + ks * 32 + lq * 8;
      float4 f0 = *(const float4*)(wr);
      float4 f1 = *(const float4*)(wr + 4);
      i32x4 p;
      p.x = (int)((unsigned)f2bf(f0.x) | ((unsigned)f2bf(f0.y) << 16));
      p.y = (int)((unsigned)f2bf(f0.z) | ((unsigned)f2bf(f0.w) << 16));
      p.z = (int)((unsigned)f2bf(f1.x) | ((unsigned)f2bf(f1.y) << 16));
      p.w = (int)((unsigned)f2bf(f1.z) | ((unsigned)f2bf(f1.w) << 16));
      bfr[nt][kk] = __builtin_bit_cast(short8, p);
    }
  }

  const int gb = tid >> 6;                   // batch owned for gate math (== w)
  const int P  = tid & 63;                   // unit-pair within this half
  float c0 = 0.f, c1 = 0.f;

  const unsigned short* xbase = xgp + (long)(d * 2 + half) * 4194304 + gb * 512 + P * 8;
  i32x4 xcur = *(const i32x4*)(xbase + (long)(d ? 1023 : 0) * 4096);

  __syncthreads();

  for (int t = 0; t < 1024; ++t){
    // pipelined bias load for t+1 (plain, compiler-tracked; fenced before poll asm)
    i32x4 xnew;
    {
      const int tn = (t < 1023) ? (t + 1) : t;
      const int t_xn = d ? (1023 - tn) : tn;
      xnew = *(const i32x4*)(xbase + (long)t_xn * 4096);
    }
    f32x4 acc[4] = {};
    if (t > 0){
      const int tag = 0x5A000000 + (t - 1);
      i32x4 pa, pb;
      const char* pp = (const char*)(hexd + (long)(d * 1024 + (t - 1)) * 1024
                                     + (long)(1 - half) * 512 + 2 * tid);
      if (tid < 256){
        asm volatile("global_load_dwordx4 %0, %1, off sc0 sc1" : "=v"(pa) : "v"(pp) : "memory");
        asm volatile("global_load_dwordx4 %0, %1, off sc0 sc1" : "=v"(pb) : "v"(pp) : "memory");
      }
      // phase 1: own-half K (local h) while the partner poll is in flight
      #pragma unroll
      for (int kk = 0; kk < 4; ++kk){
        const int ks = ((half << 2) + kk) & 7;
        short8 af = *(const short8*)&Abuf[(lm & 7) * 264 + ks * 32 + lq * 8];
        acc[0] = __builtin_amdgcn_mfma_f32_16x16x32_bf16(af, bfr[0][kk], acc[0], 0, 0, 0);
        acc[1] = __builtin_amdgcn_mfma_f32_16x16x32_bf16(af, bfr[1][kk], acc[1], 0, 0, 0);
        acc[2] = __builtin_amdgcn_mfma_f32_16x16x32_bf16(af, bfr[2][kk], acc[2], 0, 0, 0);
        acc[3] = __builtin_amdgcn_mfma_f32_16x16x32_bf16(af, bfr[3][kk], acc[3], 0, 0, 0);
      }
      if (tid < 256){
        bool useA = false; int tries = 0;
        for (;;){
          asm volatile("s_waitcnt vmcnt(1)" : "+v"(pa) :: "memory");
          if (__all((int)((pa.x == tag) && (pa.z == tag)))){ useA = true; break; }
          asm volatile("s_waitcnt vmcnt(0)" : "+v"(pb) :: "memory");
          if (__all((int)((pb.x == tag) && (pb.z == tag)))){ useA = false; break; }
          if (++tries >= 32768){ useA = false; break; }
          asm volatile("global_load_dwordx4 %0, %1, off sc0 sc1" : "=v"(pa) : "v"(pp) : "memory");
          asm volatile("global_load_dwordx4 %0, %1, off sc0 sc1" : "=v"(pb) : "v"(pp) : "memory");
        }
        asm volatile("s_waitcnt vmcnt(0)" : "+v"(pa), "+v"(pb) :: "memory");
        const i32x4 r = useA ? pa : pb;
        i32x2 pw; pw.x = r.y; pw.y = r.w;   // qwords 2*tid, 2*tid+1 -> 4 shorts
        *(i32x2*)&Abuf[(tid >> 5) * 264 + (1 - half) * 128 + ((2 * tid) & 63) * 2] = pw;
      }
    }
    __syncthreads();   // B1: full h(t-1) in Abuf
    if (t > 0){
      // phase 2: partner-half K
      #pragma unroll
      for (int kk = 4; kk < 8; ++kk){
        const int ks = ((half << 2) + kk) & 7;
        short8 af = *(const short8*)&Abuf[(lm & 7) * 264 + ks * 32 + lq * 8];
        acc[0] = __builtin_amdgcn_mfma_f32_16x16x32_bf16(af, bfr[0][kk], acc[0], 0, 0, 0);
        acc[1] = __builtin_amdgcn_mfma_f32_16x16x32_bf16(af, bfr[1][kk], acc[1], 0, 0, 0);
        acc[2] = __builtin_amdgcn_mfma_f32_16x16x32_bf16(af, bfr[2][kk], acc[2], 0, 0, 0);
        acc[3] = __builtin_amdgcn_mfma_f32_16x16x32_bf16(af, bfr[3][kk], acc[3], 0, 0, 0);
      }
    }
    // scatter C[b = (l>>4)*4+r][col] -> gbuf[b][col]  (rows 8..15 are dup garbage, skipped)
    if (l < 32){
      #pragma unroll
      for (int nt = 0; nt < 4; ++nt){
        const int col = w * 64 + nt * 16 + lm;
        #pragma unroll
        for (int r = 0; r < 4; ++r)
          gbuf[((l >> 4) * 4 + r) * 516 + col] = acc[nt][r];
      }
    }
    __syncthreads();   // B2: gbuf ready; Abuf(t-1) fully consumed
    {
      const float* gp = &gbuf[gb * 516 + 8 * P];
      f32x4 g0 = *(const f32x4*)(gp);       // unit 2P:   i,f,g,o
      f32x4 g1 = *(const f32x4*)(gp + 4);   // unit 2P+1: i,f,g,o
      const unsigned xa = (unsigned)xcur.x, xb = (unsigned)xcur.y;
      const unsigned xc = (unsigned)xcur.z, xd = (unsigned)xcur.w;
      const float gi0 = g0[0] + bf2f((unsigned short)(xa & 0xFFFFu));
      const float gf0 = g0[1] + bf2f((unsigned short)(xa >> 16));
      const float gg0 = g0[2] + bf2f((unsigned short)(xb & 0xFFFFu));
      const float go0 = g0[3] + bf2f((unsigned short)(xb >> 16));
      const float gi1 = g1[0] + bf2f((unsigned short)(xc & 0xFFFFu));
      const float gf1 = g1[1] + bf2f((unsigned short)(xc >> 16));
      const float gg1 = g1[2] + bf2f((unsigned short)(xd & 0xFFFFu));
      const float go1 = g1[3] + bf2f((unsigned short)(xd >> 16));
      c0 = fsigmoid(gf0) * c0 + fsigmoid(gi0) * ftanhf(gg0);
      c1 = fsigmoid(gf1) * c1 + fsigmoid(gi1) * ftanhf(gg1);
      const float h0 = fsigmoid(go0) * ftanhf(c0);
      const float h1 = fsigmoid(go1) * ftanhf(c1);
      const unsigned pay = (unsigned)f2bf(h0) | ((unsigned)f2bf(h1) << 16);
      // own half of h(t) -> LDS for next step's phase 1
      *(unsigned*)&Abuf[gb * 264 + half * 128 + 2 * P] = pay;
      // publish to partner (the ONLY global store in the loop)
      i32x2 st; st.x = 0x5A000000 + t; st.y = (int)pay;
      unsigned long long* sp = hexd + (long)(d * 1024 + t) * 1024 + half * 512 + gb * 64 + P;
      asm volatile("global_store_dwordx2 %0, %1, off sc0 sc1" :: "v"(sp), "v"(st) : "memory");
    }
    __syncthreads();   // B3: own-half h(t) visible before next phase 1
    xcur = xnew;
  }
}

// ---------------- post-scan repack: hexd -> hcat (cols 0..511) + hT ----------------
// hexd qword (d,t, half*512 + b*64 + P) payload hi-dword = (h[u=2p] | h[u=2p+1]<<16)
// with global pair index p = half*64 + P.
// block = (d, b, t-tile of 32). Phase 1: coalesced qword reads -> hcat dwords + LDS tile.
// Phase 2: LDS transpose -> hT dwords (t-pairs packed).
__global__ __launch_bounds__(256) void repack(
    const unsigned long long* __restrict__ hexd,
    unsigned* __restrict__ hcat32,   // [8][1024][512] dwords
    unsigned* __restrict__ hT32)     // [8][512][512] dwords
{
  const int bid = blockIdx.x, tid = threadIdx.x;
  const int d  = bid >> 8;
  const int b  = (bid >> 5) & 7;
  const int t0 = (bid & 31) * 32;
  __shared__ unsigned tile[32 * 132];   // [t_loc][p] pad
  #pragma unroll
  for (int k = 0; k < 16; ++k){
    const int idx = k * 256 + tid;          // 0..4095
    const int t_loc = idx >> 7, p = idx & 127;
    const int t = t0 + t_loc;
    const unsigned long long q =
        hexd[((long)(d * 1024 + t)) * 1024 + ((p >> 6) * 512) + (b * 64) + (p & 63)];
    const unsigned y = (unsigned)(q >> 32);
    const int t_x = d ? (1023 - t) : t;
    hcat32[((long)b * 1024 + t_x) * 512 + d * 128 + p] = y;
    tile[t_loc * 132 + p] = y;
  }
  __syncthreads();
  const int txB = d ? (992 - t0) : t0;     // 32-aligned t_x base of this tile
  #pragma unroll
  for (int k = 0; k < 16; ++k){
    const int idx = k * 256 + tid;          // 0..4095
    const int u_loc = idx >> 4, td = idx & 15;
    const int p = u_loc >> 1, half = (u_loc & 1) * 16;
    int ta, tb;
    if (d){ ta = 31 - 2 * td; tb = 30 - 2 * td; }
    else  { ta = 2 * td;      tb = 2 * td + 1; }
    const unsigned va = (tile[ta * 132 + p] >> half) & 0xFFFFu;
    const unsigned vb = (tile[tb * 132 + p] >> half) & 0xFFFFu;
    hT32[((long)b * 512 + d * 256 + u_loc) * 512 + (txB >> 1) + td] = va | (vb << 16);
  }
}

// ---------------- attention scores + softmax ----------------
__global__ __launch_bounds__(256) void attn_scores(
    const float* __restrict__ qk,   // [8192][64]: qp at cols 0..9, kp at cols 16..25
    const float* __restrict__ W2,   // [10]
    const int*   __restrict__ mask, // [8][1024]
    unsigned short* __restrict__ attn) // [8][1024][1024] bf16
{
  const int bt = blockIdx.x;
  const int b = bt >> 10;
  const int tid = threadIdx.x;
  __shared__ float red[256];
  float qv[10], w2[10];
  const float* qrow = qk + (long)bt * 64;
  #pragma unroll
  for (int x = 0; x < 10; ++x){ qv[x] = qrow[x]; w2[x] = W2[x]; }
  float sv[4];
  float smax = -3.4e38f;
  #pragma unroll
  for (int uu = 0; uu < 4; ++uu){
    const int u = tid + uu * 256;
    const float* krow = qk + (long)(b * 1024 + u) * 64 + 16;
    float s = 0.f;
    #pragma unroll
    for (int x = 0; x < 10; ++x) s += w2[x] * ftanhf(qv[x] + krow[x]);
    if (mask[b * 1024 + u] == 0) s = -3.0e38f;
    sv[uu] = s;
    smax = fmaxf(smax, s);
  }
  red[tid] = smax; __syncthreads();
  for (int off = 128; off > 0; off >>= 1){
    if (tid < off) red[tid] = fmaxf(red[tid], red[tid + off]);
    __syncthreads();
  }
  const float mx = red[0]; __syncthreads();
  float ev[4]; float lsum = 0.f;
  #pragma unroll
  for (int uu = 0; uu < 4; ++uu){ ev[uu] = fexp2((sv[uu] - mx) * LOG2E); lsum += ev[uu]; }
  red[tid] = lsum; __syncthreads();
  for (int off = 128; off > 0; off >>= 1){
    if (tid < off) red[tid] = red[tid] + red[tid + off];
    __syncthreads();
  }
  const float inv = frcp(red[0]);
  #pragma unroll
  for (int uu = 0; uu < 4; ++uu)
    attn[(long)bt * 1024 + tid + uu * 256] = f2bf(ev[uu] * inv);
}

// ---------------- launch ----------------
extern "C" void kernel_launch(void* const* d_in, const int* in_sizes, int n_in,
                              void* d_out, int out_size, void* d_ws, size_t ws_size,
                              hipStream_t stream) {
  (void)in_sizes; (void)n_in; (void)out_size; (void)ws_size;
  const float* x     = (const float*)d_in[0];
  const int*   mask  = (const int*)d_in[1];
  const float* Wih_f = (const float*)d_in[3];
  const float* Whh_f = (const float*)d_in[4];
  const float* bih_f = (const float*)d_in[5];
  const float* bhh_f = (const float*)d_in[6];
  const float* Wih_b = (const float*)d_in[7];
  const float* Whh_b = (const float*)d_in[8];
  const float* bih_b = (const float*)d_in[9];
  const float* bhh_b = (const float*)d_in[10];
  const float* W1    = (const float*)d_in[11];
  const float* W2    = (const float*)d_in[12];
  const float* W3    = (const float*)d_in[13];
  const float* b3    = (const float*)d_in[14];

  char* W = (char*)d_ws;
  unsigned short* x_bf    = (unsigned short*)(W + 0);            // 12,582,912
  unsigned short* wihcat  = (unsigned short*)(W + 12582912);     //  3,145,728
  unsigned short* w3bf    = (unsigned short*)(W + 15728640);     //  1,048,576
  unsigned short* w1p     = (unsigned short*)(W + 16777216);     //     65,536
  float*          bc      = (float*)        (W + 16842752);      //      8,192
  unsigned short* xgp     = (unsigned short*)(W + 16850944);     // 33,554,432
  unsigned long long* hexd= (unsigned long long*)(W + 50405376); // 16,777,216
  unsigned short* hcat    = (unsigned short*)(W + 67182592);     // 16,777,216
  unsigned short* hT      = (unsigned short*)(W + 83959808);     //  8,388,608
  float*          qk      = (float*)        (W + 92348416);      //  2,097,152
  unsigned short* attn    = (unsigned short*)(W + 94445568);     // 16,777,216 -> total 111,222,784

  // fused prep
  prep_fused<<<8328, 256, 0, stream>>>(x, x_bf, Wih_f, Wih_b, wihcat, W3, w3bf, W1, w1p,
                                       bih_f, bhh_f, bih_b, bhh_b, bc);

  // xg = x @ [Wih_f;Wih_b]^T + bias  -> scan-layout xgp (omode=2)
  gemm_abt<<<dim3(16, 64, 1), 256, 0, stream>>>(x_bf, 768, 0, wihcat, 768, 0, bc,
                                                xgp, 0, 0, 8192, 2048, 768, 2);
  // BiLSTM scan: 4 blocks (dir x unit-half), partner-only exchange
  lstm_scan<<<4, 512, 0, stream>>>(xgp, Whh_f, Whh_b, hexd);

  // rebuild hcat (cols 0..511) + hT from the exchange buffer
  repack<<<512, 256, 0, stream>>>(hexd, (unsigned*)hcat, (unsigned*)hT);

  // qp/kp: hcat[:, :512] @ W1pack^T -> qk fp32 [8192][64]
  gemm_abt<<<dim3(1, 64, 1), 256, 0, stream>>>(hcat, 1024, 0, w1p, 512, 0, nullptr,
                                               qk, 64, 0, 8192, 64, 512, 0);
  // scores + softmax -> attn bf16
  attn_scores<<<8192, 256, 0, stream>>>(qk, W2, mask, attn);

  // context = attn @ h (per b): A=attn[b], B=hT[b] (512x1024) -> hcat[:, 512:]
  gemm_abt<<<dim3(4, 8, 8), 256, 0, stream>>>(attn, 1024, 1048576, hT, 1024, 524288, nullptr,
                                              (void*)(hcat + 512), 1024, 1048576, 1024, 512, 1024, 1);
  // y = [h|ctx] @ W3^T + b3 -> d_out fp32
  gemm_abt<<<dim3(4, 64, 1), 256, 0, stream>>>(hcat, 1024, 0, w3bf, 1024, 0, b3,
                                               (float*)d_out, 512, 0, 8192, 512, 1024, 0);
}

// Round 2
// 1634.590 us; speedup vs baseline: 1.2271x; 1.2271x over previous
//
#include <hip/hip_runtime.h>

typedef __attribute__((ext_vector_type(4))) float  f32x4;
typedef __attribute__((ext_vector_type(8))) short  short8;
typedef __attribute__((ext_vector_type(4))) int    i32x4;
typedef __attribute__((ext_vector_type(2))) int    i32x2;

#define LOG2E 1.4426950408889634f

__device__ __forceinline__ float fexp2(float x){ float r; asm("v_exp_f32 %0, %1" : "=v"(r) : "v"(x)); return r; }
__device__ __forceinline__ float frcp (float x){ float r; asm("v_rcp_f32 %0, %1" : "=v"(r) : "v"(x)); return r; }
__device__ __forceinline__ float fsigmoid(float x){ return frcp(1.f + fexp2(-LOG2E*x)); }
__device__ __forceinline__ float ftanhf (float x){ return 1.f - 2.f*frcp(1.f + fexp2(2.f*LOG2E*x)); }

__device__ __forceinline__ unsigned short f2bf(float f){
  unsigned u = __builtin_bit_cast(unsigned, f);
  u = u + 0x7FFFu + ((u >> 16) & 1u);
  return (unsigned short)(u >> 16);
}
__device__ __forceinline__ float bf2f(unsigned short h){
  unsigned u = ((unsigned)h) << 16;
  return __builtin_bit_cast(float, u);
}

// ---------------- fused prep ----------------
// blocks [0,6144): x cast; [6144,6912): Wih_f; [6912,7680): Wih_b; [7680,8192): W3;
// [8192,8320): pack_w1; [8320,8328): pack_bias.
__global__ __launch_bounds__(256) void prep_fused(
    const float* __restrict__ x,     unsigned short* __restrict__ x_bf,
    const float* __restrict__ Wih_f, const float* __restrict__ Wih_b,
    unsigned short* __restrict__ wihcat,
    const float* __restrict__ W3,    unsigned short* __restrict__ w3bf,
    const float* __restrict__ W1,    unsigned short* __restrict__ w1p,
    const float* __restrict__ bif, const float* __restrict__ bhf,
    const float* __restrict__ bib, const float* __restrict__ bhb,
    float* __restrict__ bc)
{
  const int bid = blockIdx.x, tid = threadIdx.x;
  if (bid < 8192){
    const float* s; unsigned short* d; int i;
    if (bid < 6144)      { s = x;     d = x_bf;            i = bid * 256 + tid; }
    else if (bid < 6912) { s = Wih_f; d = wihcat;          i = (bid - 6144) * 256 + tid; }
    else if (bid < 7680) { s = Wih_b; d = wihcat + 786432; i = (bid - 6912) * 256 + tid; }
    else                 { s = W3;    d = w3bf;            i = (bid - 7680) * 256 + tid; }
    float4 f = ((const float4*)s)[i];
    uint2 o;
    o.x = (unsigned)f2bf(f.x) | ((unsigned)f2bf(f.y) << 16);
    o.y = (unsigned)f2bf(f.z) | ((unsigned)f2bf(f.w) << 16);
    ((uint2*)d)[i] = o;
  } else if (bid < 8320){
    int i = (bid - 8192) * 256 + tid;           // 0..32767
    int r = i >> 9, c = i & 511;
    float v = 0.f;
    if (r < 10) v = W1[r * 1024 + c];
    else if (r >= 16 && r < 26) v = W1[(r - 16) * 1024 + 512 + c];
    w1p[i] = f2bf(v);
  } else {
    int i = (bid - 8320) * 256 + tid;           // 0..2047
    if (i < 1024) bc[i] = bif[i] + bhf[i];
    else          bc[i] = bib[i - 1024] + bhb[i - 1024];
  }
}

// ---------------- generic bf16 GEMM: C[M,N] = A[M,K] @ B[N,K]^T (+bias) ----------------
// omode: 0 = f32 out, 1 = bf16 out, 2 = bf16 scan-layout scatter (xgp[d][g][t][b][u][gate])
__global__ __launch_bounds__(256) void gemm_abt(
    const unsigned short* __restrict__ A, long lda, long sAz,
    const unsigned short* __restrict__ B, long ldb, long sBz,
    const float* __restrict__ bias,
    void* __restrict__ Cv, long ldc, long sCz,
    int M, int N, int K, int omode)
{
  __shared__ __align__(16) unsigned short As[128 * 40];
  __shared__ __align__(16) unsigned short Bs[128 * 40];
  const int tid = threadIdx.x;
  const int m0 = blockIdx.y * 128;
  const int n0 = blockIdx.x * 128;
  const long z = blockIdx.z;
  A += z * sAz; B += z * sBz;
  const int w = tid >> 6, l = tid & 63;
  const int wm = (w >> 1) * 64, wn = (w & 1) * 64;
  const int lm = l & 15, lq = l >> 4;
  f32x4 acc[4][4] = {};
  const int sr = tid >> 1;
  const int sk = (tid & 1) * 16;
  const unsigned short* Aptr = A + (long)(m0 + sr) * lda + sk;
  const unsigned short* Bptr = B + (long)(n0 + sr) * ldb + sk;
  const bool bvalid = (n0 + sr) < N;
  const int KB = K >> 5;
  for (int kb = 0; kb < KB; ++kb){
    i32x4 av0 = *(const i32x4*)(Aptr);
    i32x4 av1 = *(const i32x4*)(Aptr + 8);
    i32x4 bv0 = {0,0,0,0}, bv1 = {0,0,0,0};
    if (bvalid){ bv0 = *(const i32x4*)(Bptr); bv1 = *(const i32x4*)(Bptr + 8); }
    Aptr += 32; Bptr += 32;
    __syncthreads();
    *(i32x4*)&As[sr * 40 + sk] = av0;  *(i32x4*)&As[sr * 40 + sk + 8] = av1;
    *(i32x4*)&Bs[sr * 40 + sk] = bv0;  *(i32x4*)&Bs[sr * 40 + sk + 8] = bv1;
    __syncthreads();
    const int koff = lq * 8;
    short8 af[4], bf[4];
    #pragma unroll
    for (int mt = 0; mt < 4; ++mt) af[mt] = *(short8*)&As[(wm + mt * 16 + lm) * 40 + koff];
    #pragma unroll
    for (int nt = 0; nt < 4; ++nt) bf[nt] = *(short8*)&Bs[(wn + nt * 16 + lm) * 40 + koff];
    #pragma unroll
    for (int mt = 0; mt < 4; ++mt)
      #pragma unroll
      for (int nt = 0; nt < 4; ++nt)
        acc[mt][nt] = __builtin_amdgcn_mfma_f32_16x16x32_bf16(af[mt], bf[nt], acc[mt][nt], 0, 0, 0);
  }
  #pragma unroll
  for (int mt = 0; mt < 4; ++mt){
    const int mbase = m0 + wm + mt * 16 + lq * 4;
    #pragma unroll
    for (int nt = 0; nt < 4; ++nt){
      const int n = n0 + wn + nt * 16 + lm;
      if (n < N){
        const float bv = bias ? bias[n] : 0.f;
        #pragma unroll
        for (int r = 0; r < 4; ++r){
          const float v = acc[mt][nt][r] + bv;
          const int m = mbase + r;
          if (omode == 2){
            const int b = m >> 10, tt = m & 1023;
            const int dd = n >> 10, gate = (n >> 8) & 3, unit = n & 255;
            const int gg = unit >> 5, u = unit & 31;
            const long idx = (long)(dd * 8 + gg) * 1048576 + (long)tt * 1024 + b * 128 + u * 4 + gate;
            ((unsigned short*)Cv)[idx] = f2bf(v);
          } else {
            const long idx = z * sCz + (long)m * ldc + n;
            if (omode == 1) ((unsigned short*)Cv)[idx] = f2bf(v);
            else            ((float*)Cv)[idx] = v;
          }
        }
      }
    }
  }
}

// ---------------- LSTM scan v11: v9 compute structure + XCD-co-located L2 exchange ----------------
// 58 blocks launched; only bid%8==0 (d=0) and bid%8==1 (d=1) work, g = bid>>3.
// With round-robin block->XCD dispatch, all 8 slice-blocks of a direction share one
// XCD, so the h exchange can go through that XCD's L2 (sc0, ~250cy RTT) instead of
// the LLC (~700cy+). Producers DUAL-publish: fast copy (sc0) into hfast (reuses the
// attn buffer, dead until attn_scores) and the authoritative sc1 copy into hexd.
// Consumers poll the fast copy a few rounds; if t==1 never resolves fast (mapping
// heuristic failed), they permanently fall back to the v9 LLC poll. Correctness
// never depends on the XCD mapping.
__global__ __launch_bounds__(256) void lstm_scan(
    const unsigned short* __restrict__ xgp,  // [d][g][t][b][u][gate] bf16
    const float* __restrict__ Whh_f, const float* __restrict__ Whh_b,
    unsigned long long* __restrict__ hexd,   // [2][1024][8][128] tagged qwords (LLC copy)
    unsigned long long* __restrict__ hfast)  // same layout, L2-local fast copy
{
  const int bid = blockIdx.x;
  if ((bid & 7) >= 2) return;              // idle filler blocks
  const int d  = bid & 7;                  // 0 or 1 -> XCD0 / XCD1
  const int g  = bid >> 3;                 // 0..7
  const int tid = threadIdx.x;
  const int w  = tid >> 6;                 // gate / poll quarter
  const int l  = tid & 63;
  const int lm = l & 15;
  const int lq = l >> 4;
  const float* Whh = d ? Whh_b : Whh_f;

  __shared__ __align__(16) unsigned short hbuf[8 * 264];     // shared [b][264]
  __shared__ float gbuf[4][32][9];                           // [gate][j][b pad9]

  // resident B fragments: wave w = gate w; rows w*256 + g*32 + nt*16 + lm; k = kt*32+lq*8
  short8 bfr[2][8];
  #pragma unroll
  for (int nt = 0; nt < 2; ++nt){
    const float* wr = Whh + (long)(w * 256 + g * 32 + nt * 16 + lm) * 256 + lq * 8;
    #pragma unroll
    for (int kt = 0; kt < 8; ++kt){
      float4 f0 = *(const float4*)(wr + kt * 32);
      float4 f1 = *(const float4*)(wr + kt * 32 + 4);
      i32x4 p;
      p.x = (unsigned)f2bf(f0.x) | ((unsigned)f2bf(f0.y) << 16);
      p.y = (unsigned)f2bf(f0.z) | ((unsigned)f2bf(f0.w) << 16);
      p.z = (unsigned)f2bf(f1.x) | ((unsigned)f2bf(f1.y) << 16);
      p.w = (unsigned)f2bf(f1.z) | ((unsigned)f2bf(f1.w) << 16);
      bfr[nt][kt] = __builtin_bit_cast(short8, p);
    }
  }

  const int gb = tid >> 5;        // b (0..7)
  const int gj = tid & 31;        // unit local to slice
  float c_state = 0.f;
  bool fastok = true;

  const unsigned short* xbase = xgp + (long)(d * 8 + g) * 1048576 + gb * 128 + gj * 4;
  i32x2 xcur = *(const i32x2*)(xbase + (long)(d ? 1023 : 0) * 1024);

  for (int t = 0; t < 1024; ++t){
    // pipelined bias load for t+1 (plain, compiler-tracked; fenced before poll asm)
    i32x2 xnew;
    {
      const int tn = (t < 1023) ? (t + 1) : t;
      const int t_xn = d ? (1023 - tn) : tn;
      xnew = *(const i32x2*)(xbase + (long)t_xn * 1024);
    }
    f32x4 acc0 = {0.f,0.f,0.f,0.f}, acc1 = {0.f,0.f,0.f,0.f};
    if (t > 0){
      const int tag = 0x5A000000 + (t - 1);
      const long roff = (long)(d * 1024 + (t - 1)) * 1024;
      i32x4 r0, r1;
      bool got = false;
      if (fastok){
        // fast path: poll the L2-local copy (same-XCD heuristic)
        const char* qf0 = (const char*)(hfast + roff) + (2 * w) * 1024 + l * 16;
        const char* qf1 = qf0 + 1024;
        i32x4 a0, a1;
        const int T1 = (t == 1) ? 96 : 12;
        for (int rr = 0; rr < T1; ++rr){
          asm volatile("global_load_dwordx4 %0, %1, off sc0" : "=v"(a0) : "v"(qf0) : "memory");
          asm volatile("global_load_dwordx4 %0, %1, off sc0" : "=v"(a1) : "v"(qf1) : "memory");
          asm volatile("s_waitcnt vmcnt(0)" : "+v"(a0), "+v"(a1) :: "memory");
          if (__all((int)((a0.x == tag) && (a0.z == tag) && (a1.x == tag) && (a1.z == tag)))){
            got = true; break;
          }
        }
        if (got){ r0 = a0; r1 = a1; }
        else if (t == 1) fastok = false;   // mapping heuristic failed -> LLC path forever
      }
      if (!got){
        // slow path: v9 LLC poll (always correct)
        const char* pb0 = (const char*)(hexd + roff) + (2 * w) * 1024 + l * 16;
        const char* pb1 = pb0 + 1024;
        i32x4 a0, a1, b0, b1;
        asm volatile("global_load_dwordx4 %0, %1, off sc0 sc1" : "=v"(a0) : "v"(pb0) : "memory");
        asm volatile("global_load_dwordx4 %0, %1, off sc0 sc1" : "=v"(a1) : "v"(pb1) : "memory");
        asm volatile("global_load_dwordx4 %0, %1, off sc0 sc1" : "=v"(b0) : "v"(pb0) : "memory");
        asm volatile("global_load_dwordx4 %0, %1, off sc0 sc1" : "=v"(b1) : "v"(pb1) : "memory");
        bool useA = false;
        int tries = 0;
        for (;;){
          asm volatile("s_waitcnt vmcnt(2)" : "+v"(a0), "+v"(a1) :: "memory");
          if (__all((int)((a0.x == tag) && (a0.z == tag) && (a1.x == tag) && (a1.z == tag)))){
            useA = true; break;
          }
          asm volatile("s_waitcnt vmcnt(0)" : "+v"(b0), "+v"(b1) :: "memory");
          if (__all((int)((b0.x == tag) && (b0.z == tag) && (b1.x == tag) && (b1.z == tag)))){
            useA = false; break;
          }
          if (++tries >= 32768){ useA = false; break; }
          asm volatile("global_load_dwordx4 %0, %1, off sc0 sc1" : "=v"(a0) : "v"(pb0) : "memory");
          asm volatile("global_load_dwordx4 %0, %1, off sc0 sc1" : "=v"(a1) : "v"(pb1) : "memory");
          asm volatile("global_load_dwordx4 %0, %1, off sc0 sc1" : "=v"(b0) : "v"(pb0) : "memory");
          asm volatile("global_load_dwordx4 %0, %1, off sc0 sc1" : "=v"(b1) : "v"(pb1) : "memory");
        }
        asm volatile("s_waitcnt vmcnt(0)" : "+v"(b0), "+v"(b1) :: "memory");
        r0 = useA ? a0 : b0;
        r1 = useA ? a1 : b1;
      }
      i32x2 p0; p0.x = r0.y; p0.y = r0.w;
      i32x2 p1; p1.x = r1.y; p1.y = r1.w;
      *(i32x2*)&hbuf[(2 * w)     * 264 + l * 4] = p0;
      *(i32x2*)&hbuf[(2 * w + 1) * 264 + l * 4] = p1;
    }
    __syncthreads();   // B1: hbuf complete (all quarters)
    if (t > 0){
      #pragma unroll
      for (int kt = 0; kt < 8; ++kt){
        short8 af = *(const short8*)&hbuf[(lm & 7) * 264 + kt * 32 + lq * 8];
        acc0 = __builtin_amdgcn_mfma_f32_16x16x32_bf16(af, bfr[0][kt], acc0, 0, 0, 0);
        acc1 = __builtin_amdgcn_mfma_f32_16x16x32_bf16(af, bfr[1][kt], acc1, 0, 0, 0);
      }
    }
    // C[b=lq*4+r][j=nt*16+lm] -> gbuf[w][j][b]
    if (l < 32){
      #pragma unroll
      for (int r = 0; r < 4; ++r){
        gbuf[w][lm][lq * 4 + r]      = acc0[r];
        gbuf[w][16 + lm][lq * 4 + r] = acc1[r];
      }
    }
    __syncthreads();   // B2: gbuf visible; also protects hbuf reuse next step
    {
      const float gi = gbuf[0][gj][gb] + bf2f((unsigned short)((unsigned)xcur.x & 0xFFFFu));
      const float gf = gbuf[1][gj][gb] + bf2f((unsigned short)((unsigned)xcur.x >> 16));
      const float gG = gbuf[2][gj][gb] + bf2f((unsigned short)((unsigned)xcur.y & 0xFFFFu));
      const float go = gbuf[3][gj][gb] + bf2f((unsigned short)((unsigned)xcur.y >> 16));
      c_state = fsigmoid(gf) * c_state + fsigmoid(gi) * ftanhf(gG);
      const float h = fsigmoid(go) * ftanhf(c_state);
      const unsigned short hb16 = f2bf(h);
      // publish: fast (L2-local) copy first, then the authoritative LLC copy
      const int hp = __shfl_xor((int)hb16, 1);
      if (!(gj & 1)){
        i32x2 st;
        st.x = 0x5A000000 + t;
        st.y = (int)(((unsigned)hb16) | (((unsigned)hp) << 16));
        const long soff = (long)(d * 1024 + t) * 1024 + gb * 128 + g * 16 + (gj >> 1);
        unsigned long long* spf = hfast + soff;
        unsigned long long* sps = hexd + soff;
        asm volatile("global_store_dwordx2 %0, %1, off sc0"     :: "v"(spf), "v"(st) : "memory");
        asm volatile("global_store_dwordx2 %0, %1, off sc0 sc1" :: "v"(sps), "v"(st) : "memory");
      }
    }
    xcur = xnew;
  }
}

// ---------------- post-scan repack: hexd -> hcat (cols 0..511) + hT ----------------
// hexd qword (d,t, b*128+p) payload hi-dword = (h[u=2p] | h[u=2p+1]<<16).
// block = (d, b, t-tile of 32). Phase 1: coalesced qword reads -> hcat dwords + LDS tile.
// Phase 2: LDS transpose -> hT dwords (t-pairs packed).
__global__ __launch_bounds__(256) void repack(
    const unsigned long long* __restrict__ hexd,
    unsigned* __restrict__ hcat32,   // [8][1024][512] dwords
    unsigned* __restrict__ hT32)     // [8][512][512] dwords
{
  const int bid = blockIdx.x, tid = threadIdx.x;
  const int d  = bid >> 8;
  const int b  = (bid >> 5) & 7;
  const int t0 = (bid & 31) * 32;
  __shared__ unsigned tile[32 * 132];   // [t_loc][p] pad
  #pragma unroll
  for (int k = 0; k < 16; ++k){
    const int idx = k * 256 + tid;          // 0..4095
    const int t_loc = idx >> 7, p = idx & 127;
    const int t = t0 + t_loc;
    const unsigned long long q = hexd[((long)(d * 1024 + t)) * 1024 + b * 128 + p];
    const unsigned y = (unsigned)(q >> 32);
    const int t_x = d ? (1023 - t) : t;
    hcat32[((long)b * 1024 + t_x) * 512 + d * 128 + p] = y;
    tile[t_loc * 132 + p] = y;
  }
  __syncthreads();
  const int txB = d ? (992 - t0) : t0;     // 32-aligned t_x base of this tile
  #pragma unroll
  for (int k = 0; k < 16; ++k){
    const int idx = k * 256 + tid;          // 0..4095
    const int u_loc = idx >> 4, td = idx & 15;
    const int p = u_loc >> 1, half = (u_loc & 1) * 16;
    int ta, tb;
    if (d){ ta = 31 - 2 * td; tb = 30 - 2 * td; }
    else  { ta = 2 * td;      tb = 2 * td + 1; }
    const unsigned va = (tile[ta * 132 + p] >> half) & 0xFFFFu;
    const unsigned vb = (tile[tb * 132 + p] >> half) & 0xFFFFu;
    hT32[((long)b * 512 + d * 256 + u_loc) * 512 + (txB >> 1) + td] = va | (vb << 16);
  }
}

// ---------------- attention scores + softmax ----------------
__global__ __launch_bounds__(256) void attn_scores(
    const float* __restrict__ qk,   // [8192][64]: qp at cols 0..9, kp at cols 16..25
    const float* __restrict__ W2,   // [10]
    const int*   __restrict__ mask, // [8][1024]
    unsigned short* __restrict__ attn) // [8][1024][1024] bf16
{
  const int bt = blockIdx.x;
  const int b = bt >> 10;
  const int tid = threadIdx.x;
  __shared__ float red[256];
  float qv[10], w2[10];
  const float* qrow = qk + (long)bt * 64;
  #pragma unroll
  for (int x = 0; x < 10; ++x){ qv[x] = qrow[x]; w2[x] = W2[x]; }
  float sv[4];
  float smax = -3.4e38f;
  #pragma unroll
  for (int uu = 0; uu < 4; ++uu){
    const int u = tid + uu * 256;
    const float* krow = qk + (long)(b * 1024 + u) * 64 + 16;
    float s = 0.f;
    #pragma unroll
    for (int x = 0; x < 10; ++x) s += w2[x] * ftanhf(qv[x] + krow[x]);
    if (mask[b * 1024 + u] == 0) s = -3.0e38f;
    sv[uu] = s;
    smax = fmaxf(smax, s);
  }
  red[tid] = smax; __syncthreads();
  for (int off = 128; off > 0; off >>= 1){
    if (tid < off) red[tid] = fmaxf(red[tid], red[tid + off]);
    __syncthreads();
  }
  const float mx = red[0]; __syncthreads();
  float ev[4]; float lsum = 0.f;
  #pragma unroll
  for (int uu = 0; uu < 4; ++uu){ ev[uu] = fexp2((sv[uu] - mx) * LOG2E); lsum += ev[uu]; }
  red[tid] = lsum; __syncthreads();
  for (int off = 128; off > 0; off >>= 1){
    if (tid < off) red[tid] = red[tid] + red[tid + off];
    __syncthreads();
  }
  const float inv = frcp(red[0]);
  #pragma unroll
  for (int uu = 0; uu < 4; ++uu)
    attn[(long)bt * 1024 + tid + uu * 256] = f2bf(ev[uu] * inv);
}

// ---------------- launch ----------------
extern "C" void kernel_launch(void* const* d_in, const int* in_sizes, int n_in,
                              void* d_out, int out_size, void* d_ws, size_t ws_size,
                              hipStream_t stream) {
  (void)in_sizes; (void)n_in; (void)out_size; (void)ws_size;
  const float* x     = (const float*)d_in[0];
  const int*   mask  = (const int*)d_in[1];
  const float* Wih_f = (const float*)d_in[3];
  const float* Whh_f = (const float*)d_in[4];
  const float* bih_f = (const float*)d_in[5];
  const float* bhh_f = (const float*)d_in[6];
  const float* Wih_b = (const float*)d_in[7];
  const float* Whh_b = (const float*)d_in[8];
  const float* bih_b = (const float*)d_in[9];
  const float* bhh_b = (const float*)d_in[10];
  const float* W1    = (const float*)d_in[11];
  const float* W2    = (const float*)d_in[12];
  const float* W3    = (const float*)d_in[13];
  const float* b3    = (const float*)d_in[14];

  char* W = (char*)d_ws;
  unsigned short* x_bf    = (unsigned short*)(W + 0);            // 12,582,912
  unsigned short* wihcat  = (unsigned short*)(W + 12582912);     //  3,145,728
  unsigned short* w3bf    = (unsigned short*)(W + 15728640);     //  1,048,576
  unsigned short* w1p     = (unsigned short*)(W + 16777216);     //     65,536
  float*          bc      = (float*)        (W + 16842752);      //      8,192
  unsigned short* xgp     = (unsigned short*)(W + 16850944);     // 33,554,432
  unsigned long long* hexd= (unsigned long long*)(W + 50405376); // 16,777,216
  unsigned short* hcat    = (unsigned short*)(W + 67182592);     // 16,777,216
  unsigned short* hT      = (unsigned short*)(W + 83959808);     //  8,388,608
  float*          qk      = (float*)        (W + 92348416);      //  2,097,152
  unsigned short* attn    = (unsigned short*)(W + 94445568);     // 16,777,216 -> total 111,222,784
  // fast exchange copy aliases the attn buffer (dead until attn_scores; 16 MB, same size as hexd)
  unsigned long long* hfast = (unsigned long long*)attn;

  // fused prep
  prep_fused<<<8328, 256, 0, stream>>>(x, x_bf, Wih_f, Wih_b, wihcat, W3, w3bf, W1, w1p,
                                       bih_f, bhh_f, bih_b, bhh_b, bc);

  // xg = x @ [Wih_f;Wih_b]^T + bias  -> scan-layout xgp (omode=2)
  gemm_abt<<<dim3(16, 64, 1), 256, 0, stream>>>(x_bf, 768, 0, wihcat, 768, 0, bc,
                                                xgp, 0, 0, 8192, 2048, 768, 2);
  // BiLSTM scan: 58 blocks, only bid%8 in {0,1} work -> per-direction XCD co-location
  lstm_scan<<<58, 256, 0, stream>>>(xgp, Whh_f, Whh_b, hexd, hfast);

  // rebuild hcat (cols 0..511) + hT from the exchange buffer
  repack<<<512, 256, 0, stream>>>(hexd, (unsigned*)hcat, (unsigned*)hT);

  // qp/kp: hcat[:, :512] @ W1pack^T -> qk fp32 [8192][64]
  gemm_abt<<<dim3(1, 64, 1), 256, 0, stream>>>(hcat, 1024, 0, w1p, 512, 0, nullptr,
                                               qk, 64, 0, 8192, 64, 512, 0);
  // scores + softmax -> attn bf16
  attn_scores<<<8192, 256, 0, stream>>>(qk, W2, mask, attn);

  // context = attn @ h (per b): A=attn[b], B=hT[b] (512x1024) -> hcat[:, 512:]
  gemm_abt<<<dim3(4, 8, 8), 256, 0, stream>>>(attn, 1024, 1048576, hT, 1024, 524288, nullptr,
                                              (void*)(hcat + 512), 1024, 1048576, 1024, 512, 1024, 1);
  // y = [h|ctx] @ W3^T + b3 -> d_out fp32
  gemm_abt<<<dim3(4, 64, 1), 256, 0, stream>>>(hcat, 1024, 0, w3bf, 1024, 0, b3,
                                               (float*)d_out, 512, 0, 8192, 512, 1024, 0);
}